// Round 6
// baseline (415.029 us; speedup 1.0000x reference)
//
#include <hip/hip_runtime.h>
#include <hip/hip_bf16.h>

#define D 64
#define GRAPHS 128

using bf16x8 = __attribute__((ext_vector_type(8))) short;   // 8 bf16 (4 VGPRs)
using f32x4  = __attribute__((ext_vector_type(4))) float;

// ---------------- small helpers ----------------

__device__ __forceinline__ float bf2f(unsigned short u) {
    return __uint_as_float(((unsigned)u) << 16);
}
__device__ __forceinline__ unsigned short f2bf(float f) {
    unsigned u = __float_as_uint(f);
    unsigned r = (u + 0x7FFFu + ((u >> 16) & 1u)) >> 16;   // RNE
    return (unsigned short)r;
}

// ---------------- gcn_norm / CSR build ----------------

// 4 edges/thread: int4 loads + 4 independent atomics in flight
__global__ void deg_kernel(const int* __restrict__ dst, int* __restrict__ deg, int E) {
    int e4 = (blockIdx.x * blockDim.x + threadIdx.x) * 4;
    if (e4 + 4 <= E) {
        int4 d = *(const int4*)(dst + e4);
        atomicAdd(&deg[d.x], 1);
        atomicAdd(&deg[d.y], 1);
        atomicAdd(&deg[d.z], 1);
        atomicAdd(&deg[d.w], 1);
    } else {
        for (int e = e4; e < E; ++e) atomicAdd(&deg[dst[e]], 1);
    }
}

__global__ void dinv_kernel(const int* __restrict__ deg, float* __restrict__ dinv, int N) {
    int i = blockIdx.x * blockDim.x + threadIdx.x;
    if (i < N) {
        int d = deg[i];
        dinv[i] = d > 0 ? rsqrtf((float)d) : 0.0f;
    }
}

__global__ void block_sum_kernel(const int* __restrict__ deg, int* __restrict__ bsum, int N) {
    __shared__ int s[256];
    int i = blockIdx.x * 256 + threadIdx.x;
    s[threadIdx.x] = (i < N) ? deg[i] : 0;
    __syncthreads();
    for (int st = 128; st > 0; st >>= 1) {
        if (threadIdx.x < st) s[threadIdx.x] += s[threadIdx.x + st];
        __syncthreads();
    }
    if (threadIdx.x == 0) bsum[blockIdx.x] = s[0];
}

__global__ void scan_bsum_kernel(const int* __restrict__ bsum, int* __restrict__ boff, int NB) {
    if (NB <= 256) {
        __shared__ int s[256];
        int i = threadIdx.x;
        int v = (i < NB) ? bsum[i] : 0;
        s[i] = v;
        __syncthreads();
        for (int st = 1; st < 256; st <<= 1) {
            int add = (i >= st) ? s[i - st] : 0;
            __syncthreads();
            s[i] += add;
            __syncthreads();
        }
        if (i < NB) boff[i] = s[i] - v;
    } else if (threadIdx.x == 0) {
        int run = 0;
        for (int i = 0; i < NB; ++i) { boff[i] = run; run += bsum[i]; }
    }
}

__global__ void block_scan_kernel(const int* __restrict__ deg, const int* __restrict__ boff,
                                  int* __restrict__ rowstart, int* __restrict__ cursor, int N) {
    __shared__ int s[256];
    int i = blockIdx.x * 256 + threadIdx.x;
    int v = (i < N) ? deg[i] : 0;
    s[threadIdx.x] = v;
    __syncthreads();
    for (int st = 1; st < 256; st <<= 1) {
        int add = (threadIdx.x >= st) ? s[threadIdx.x - st] : 0;
        __syncthreads();
        s[threadIdx.x] += add;
        __syncthreads();
    }
    if (i < N) {
        int excl = boff[blockIdx.x] + s[threadIdx.x] - v;
        rowstart[i] = excl;
        cursor[i]   = excl;
    }
}

// 4 edges/thread: int4 loads of src/dst, 4 independent gather+atomic+store chains
__global__ void scatter_kernel(const int* __restrict__ src, const int* __restrict__ dst,
                               const float* __restrict__ dinv, int* __restrict__ cursor,
                               int2* __restrict__ ep, int E) {
    int e4 = (blockIdx.x * blockDim.x + threadIdx.x) * 4;
    if (e4 + 4 <= E) {
        int4 s = *(const int4*)(src + e4);
        int4 d = *(const int4*)(dst + e4);
        float w0 = dinv[s.x] * dinv[d.x];
        float w1 = dinv[s.y] * dinv[d.y];
        float w2 = dinv[s.z] * dinv[d.z];
        float w3 = dinv[s.w] * dinv[d.w];
        int p0 = atomicAdd(&cursor[d.x], 1);
        int p1 = atomicAdd(&cursor[d.y], 1);
        int p2 = atomicAdd(&cursor[d.z], 1);
        int p3 = atomicAdd(&cursor[d.w], 1);
        ep[p0] = make_int2(s.x, __float_as_int(w0));
        ep[p1] = make_int2(s.y, __float_as_int(w1));
        ep[p2] = make_int2(s.z, __float_as_int(w2));
        ep[p3] = make_int2(s.w, __float_as_int(w3));
    } else {
        for (int e = e4; e < E; ++e) {
            int dd = dst[e], ss = src[e];
            float w = dinv[ss] * dinv[dd];
            int pos = atomicAdd(&cursor[dd], 1);
            ep[pos] = make_int2(ss, __float_as_int(w));
        }
    }
}

// ---------------- x -> bf16 into H slot 0 ----------------

__global__ void xcvt_kernel(const float* __restrict__ x, unsigned short* __restrict__ H, int total) {
    int i = blockIdx.x * blockDim.x + threadIdx.x;
    if (i < total) {
        int n = i >> 6, f = i & 63;
        H[(size_t)n * 256 + f] = f2bf(x[i]);
    }
}

// ---------------- pure gather: out_row = sum_e w_e * in_row[src_e] ----------------
// Wave per dst node. Half-wave scheme: lanes 0-31 process even edges, lanes
// 32-63 odd edges; each lane loads ushort2 (2 features). 8-chunk unroll ->
// 16 edges per iteration, 16 row-lines in flight per wave.

#define GROWS 8   // 512 threads/block

__global__ __launch_bounds__(512, 8)
void gather_kernel(const unsigned short* __restrict__ in,   // H + slot_in*64
                   unsigned short* __restrict__ out,        // H + slot_out*64
                   const int* __restrict__ rowstart, const int* __restrict__ deg,
                   const int2* __restrict__ ep, int N) {
    int wid = blockIdx.x * GROWS + (threadIdx.x >> 6);
    if (wid >= N) return;
    int lane = threadIdx.x & 63;
    int half = lane >> 5;          // which edge of the pair
    int fl   = (lane & 31) * 2;    // feature base (2 features per lane)

    int start = __builtin_amdgcn_readfirstlane(rowstart[wid]);
    int cnt   = __builtin_amdgcn_readfirstlane(deg[wid]);

    float2 a0 = {0.f, 0.f}, a1 = a0, a2 = a0, a3 = a0, a4 = a0, a5 = a0, a6 = a0, a7 = a0;
    int i = 0;
    for (; i + 16 <= cnt; i += 16) {
        int2 e0 = ep[start + i +  0 + half];
        int2 e1 = ep[start + i +  2 + half];
        int2 e2 = ep[start + i +  4 + half];
        int2 e3 = ep[start + i +  6 + half];
        int2 e4 = ep[start + i +  8 + half];
        int2 e5 = ep[start + i + 10 + half];
        int2 e6 = ep[start + i + 12 + half];
        int2 e7 = ep[start + i + 14 + half];
        unsigned u0 = *(const unsigned*)(in + (size_t)(unsigned)e0.x * 256 + fl);
        unsigned u1 = *(const unsigned*)(in + (size_t)(unsigned)e1.x * 256 + fl);
        unsigned u2 = *(const unsigned*)(in + (size_t)(unsigned)e2.x * 256 + fl);
        unsigned u3 = *(const unsigned*)(in + (size_t)(unsigned)e3.x * 256 + fl);
        unsigned u4 = *(const unsigned*)(in + (size_t)(unsigned)e4.x * 256 + fl);
        unsigned u5 = *(const unsigned*)(in + (size_t)(unsigned)e5.x * 256 + fl);
        unsigned u6 = *(const unsigned*)(in + (size_t)(unsigned)e6.x * 256 + fl);
        unsigned u7 = *(const unsigned*)(in + (size_t)(unsigned)e7.x * 256 + fl);
        float w0 = __int_as_float(e0.y), w1 = __int_as_float(e1.y);
        float w2 = __int_as_float(e2.y), w3 = __int_as_float(e3.y);
        float w4 = __int_as_float(e4.y), w5 = __int_as_float(e5.y);
        float w6 = __int_as_float(e6.y), w7 = __int_as_float(e7.y);
        a0.x = fmaf(w0, bf2f((unsigned short)u0), a0.x); a0.y = fmaf(w0, bf2f((unsigned short)(u0 >> 16)), a0.y);
        a1.x = fmaf(w1, bf2f((unsigned short)u1), a1.x); a1.y = fmaf(w1, bf2f((unsigned short)(u1 >> 16)), a1.y);
        a2.x = fmaf(w2, bf2f((unsigned short)u2), a2.x); a2.y = fmaf(w2, bf2f((unsigned short)(u2 >> 16)), a2.y);
        a3.x = fmaf(w3, bf2f((unsigned short)u3), a3.x); a3.y = fmaf(w3, bf2f((unsigned short)(u3 >> 16)), a3.y);
        a4.x = fmaf(w4, bf2f((unsigned short)u4), a4.x); a4.y = fmaf(w4, bf2f((unsigned short)(u4 >> 16)), a4.y);
        a5.x = fmaf(w5, bf2f((unsigned short)u5), a5.x); a5.y = fmaf(w5, bf2f((unsigned short)(u5 >> 16)), a5.y);
        a6.x = fmaf(w6, bf2f((unsigned short)u6), a6.x); a6.y = fmaf(w6, bf2f((unsigned short)(u6 >> 16)), a6.y);
        a7.x = fmaf(w7, bf2f((unsigned short)u7), a7.x); a7.y = fmaf(w7, bf2f((unsigned short)(u7 >> 16)), a7.y);
    }
    for (; i + 2 <= cnt; i += 2) {
        int2 e = ep[start + i + half];
        unsigned u = *(const unsigned*)(in + (size_t)(unsigned)e.x * 256 + fl);
        float w = __int_as_float(e.y);
        a0.x = fmaf(w, bf2f((unsigned short)u), a0.x);
        a0.y = fmaf(w, bf2f((unsigned short)(u >> 16)), a0.y);
    }
    if (i < cnt) {   // odd tail: only half 0 contributes
        int2 e = ep[start + i];
        unsigned u = *(const unsigned*)(in + (size_t)(unsigned)e.x * 256 + fl);
        float w = half == 0 ? __int_as_float(e.y) : 0.0f;
        a0.x = fmaf(w, bf2f((unsigned short)u), a0.x);
        a0.y = fmaf(w, bf2f((unsigned short)(u >> 16)), a0.y);
    }

    float ax = ((a0.x + a1.x) + (a2.x + a3.x)) + ((a4.x + a5.x) + (a6.x + a7.x));
    float ay = ((a0.y + a1.y) + (a2.y + a3.y)) + ((a4.y + a5.y) + (a6.y + a7.y));
    ax += __shfl_xor(ax, 32, 64);
    ay += __shfl_xor(ay, 32, 64);
    if (half == 0) {
        unsigned pk = (unsigned)f2bf(ax) | ((unsigned)f2bf(ay) << 16);
        *(unsigned*)(out + (size_t)wid * 256 + fl) = pk;
    }
}

// ---------------- W -> per-lane MFMA B-fragment layout (bf16) ----------------
// Wfrag[kt][ct][lane][j]: B[k= kt*32 + (lane>>4)*8 + j][n= ct*16 + (lane&15)]

__global__ void wfrag_kernel(const float* __restrict__ W, unsigned short* __restrict__ Wfrag) {
    int i = blockIdx.x * 256 + threadIdx.x;   // total 8*4*64*8 = 16384
    if (i >= 16384) return;
    int j = i & 7, lane = (i >> 3) & 63, ct = (i >> 9) & 3, kt = i >> 11;
    int n = ct * 16 + (lane & 15);
    int k = kt * 32 + (lane >> 4) * 8 + j;
    Wfrag[i] = f2bf(W[k * 64 + n]);           // W viewed as [256][64]
}

// ---------------- layer projection: C[N x 64] = H[N x 256] @ Wflat[256 x 64] ----------------

template<int MODE>
__global__ __launch_bounds__(256, 4)
void tag_gemm_kernel(const unsigned short* __restrict__ H,
                     const unsigned short* __restrict__ Wfrag,
                     const float* __restrict__ bias, const float* __restrict__ alpha,
                     const float* __restrict__ Wout,
                     unsigned short* __restrict__ H2, float* __restrict__ nscal, int N) {
    int w = threadIdx.x >> 6, lane = threadIdx.x & 63;
    int m = lane & 15, quad = lane >> 4;
    int rowbase = blockIdx.x * 64 + w * 16;
    int arow = rowbase + m;
    size_t aoff = (size_t)min(arow, N - 1) * 256 + quad * 8;

    f32x4 acc0 = {0.f, 0.f, 0.f, 0.f}, acc1 = acc0, acc2 = acc0, acc3 = acc0;
#pragma unroll
    for (int kt = 0; kt < 8; ++kt) {
        bf16x8 A = *(const bf16x8*)(H + aoff + kt * 32);
        const unsigned short* wf = Wfrag + ((size_t)(kt * 4) * 64 + lane) * 8;
        bf16x8 B0 = *(const bf16x8*)(wf + 0 * 64 * 8);
        bf16x8 B1 = *(const bf16x8*)(wf + 1 * 64 * 8);
        bf16x8 B2 = *(const bf16x8*)(wf + 2 * 64 * 8);
        bf16x8 B3 = *(const bf16x8*)(wf + 3 * 64 * 8);
        acc0 = __builtin_amdgcn_mfma_f32_16x16x32_bf16(A, B0, acc0, 0, 0, 0);
        acc1 = __builtin_amdgcn_mfma_f32_16x16x32_bf16(A, B1, acc1, 0, 0, 0);
        acc2 = __builtin_amdgcn_mfma_f32_16x16x32_bf16(A, B2, acc2, 0, 0, 0);
        acc3 = __builtin_amdgcn_mfma_f32_16x16x32_bf16(A, B3, acc3, 0, 0, 0);
    }

    float al = alpha[0];
    f32x4 accs[4] = {acc0, acc1, acc2, acc3};
    if (MODE == 2) {
#pragma unroll
        for (int ct = 0; ct < 4; ++ct) {
            int col = ct * 16 + m;
            float b = bias[col];
#pragma unroll
            for (int r = 0; r < 4; ++r) {
                int row = rowbase + quad * 4 + r;
                if (row < N) {
                    float v = accs[ct][r] + b;
                    v = v >= 0.f ? v : al * v;
                    H2[(size_t)row * 256 + col] = f2bf(v);
                }
            }
        }
    } else {
        float rv0 = 0.f, rv1 = 0.f, rv2 = 0.f, rv3 = 0.f;
#pragma unroll
        for (int ct = 0; ct < 4; ++ct) {
            int col = ct * 16 + m;
            float b = bias[col], wo = Wout[col];
            float v;
            v = accs[ct][0] + b; v = v >= 0.f ? v : al * v; rv0 = fmaf(v, wo, rv0);
            v = accs[ct][1] + b; v = v >= 0.f ? v : al * v; rv1 = fmaf(v, wo, rv1);
            v = accs[ct][2] + b; v = v >= 0.f ? v : al * v; rv2 = fmaf(v, wo, rv2);
            v = accs[ct][3] + b; v = v >= 0.f ? v : al * v; rv3 = fmaf(v, wo, rv3);
        }
        float rv[4] = {rv0, rv1, rv2, rv3};
#pragma unroll
        for (int r = 0; r < 4; ++r) {
            float v = rv[r];
            v += __shfl_xor(v, 8, 16);
            v += __shfl_xor(v, 4, 16);
            v += __shfl_xor(v, 2, 16);
            v += __shfl_xor(v, 1, 16);
            int row = rowbase + quad * 4 + r;
            if (m == 0 && row < N) nscal[row] = v;
        }
    }
}

// ---------------- segment-sum + output init ----------------

__global__ void init_out_kernel(float* __restrict__ out, const float* __restrict__ bout, int n) {
    int i = threadIdx.x;
    if (i < n) out[i] = bout[0];
}

#define SEG_BLOCKS 128

__global__ void segsum_kernel(const float* __restrict__ s, const int* __restrict__ batch,
                              float* __restrict__ out, int N) {
    __shared__ float bins[GRAPHS];
    for (int i = threadIdx.x; i < GRAPHS; i += 256) bins[i] = 0.0f;
    __syncthreads();
    int chunk = (N + SEG_BLOCKS - 1) / SEG_BLOCKS;
    int lo = blockIdx.x * chunk;
    int hi = min(lo + chunk, N);
    for (int i = lo + threadIdx.x; i < hi; i += 256)
        atomicAdd(&bins[batch[i]], s[i]);
    __syncthreads();
    for (int g = threadIdx.x; g < GRAPHS; g += 256) {
        float v = bins[g];
        if (v != 0.0f) atomicAdd(&out[g], v);
    }
}

extern "C" void kernel_launch(void* const* d_in, const int* in_sizes, int n_in,
                              void* d_out, int out_size, void* d_ws, size_t ws_size,
                              hipStream_t stream) {
    const float* x     = (const float*)d_in[0];
    const int*   ei    = (const int*)d_in[1];
    const int*   batch = (const int*)d_in[2];
    const float* W0    = (const float*)d_in[3];
    const float* b0    = (const float*)d_in[4];
    const float* W1    = (const float*)d_in[5];
    const float* b1    = (const float*)d_in[6];
    const float* a0    = (const float*)d_in[7];
    const float* a1    = (const float*)d_in[8];
    const float* Wout  = (const float*)d_in[9];
    const float* bout  = (const float*)d_in[10];

    const int N = in_sizes[0] / D;
    const int E = in_sizes[1] / 2;
    const int* src = ei;
    const int* dst = ei + E;

    size_t off = 0;
    auto alloc = [&](size_t bytes) -> void* {
        void* p = (char*)d_ws + off;
        off = (off + bytes + 255) & ~(size_t)255;
        return p;
    };
    const int NB = (N + 255) / 256;
    int*   deg      = (int*)alloc((size_t)N * 4);
    int*   rowstart = (int*)alloc((size_t)N * 4);
    int*   cursor   = (int*)alloc((size_t)N * 4);
    float* dinv     = (float*)alloc((size_t)N * 4);
    int*   bsum     = (int*)alloc((size_t)NB * 4);
    int*   boff     = (int*)alloc((size_t)NB * 4);
    int2*  epack    = (int2*)alloc((size_t)E * 8);
    unsigned short* HA = (unsigned short*)alloc((size_t)N * 256 * 2);  // [N][4][64] bf16
    unsigned short* HB = (unsigned short*)alloc((size_t)N * 256 * 2);
    unsigned short* WF0 = (unsigned short*)alloc(16384 * 2);
    unsigned short* WF1 = (unsigned short*)alloc(16384 * 2);
    float* nscal    = (float*)alloc((size_t)N * 4);

    const int EB4 = (E / 4 + 255) / 256;         // 4-edges-per-thread blocks
    const int NG = (N + GROWS - 1) / GROWS;      // gather blocks (512 thr)
    const int NM = (N + 63) / 64;                // gemm blocks (256 thr)

    // --- gcn_norm + CSR build + weight prep ---
    hipMemsetAsync(deg, 0, (size_t)N * 4, stream);
    deg_kernel<<<EB4, 256, 0, stream>>>(dst, deg, E);
    dinv_kernel<<<NB, 256, 0, stream>>>(deg, dinv, N);
    block_sum_kernel<<<NB, 256, 0, stream>>>(deg, bsum, N);
    scan_bsum_kernel<<<1, 256, 0, stream>>>(bsum, boff, NB);
    block_scan_kernel<<<NB, 256, 0, stream>>>(deg, boff, rowstart, cursor, N);
    scatter_kernel<<<EB4, 256, 0, stream>>>(src, dst, dinv, cursor, epack, E);
    wfrag_kernel<<<64, 256, 0, stream>>>(W0, WF0);
    wfrag_kernel<<<64, 256, 0, stream>>>(W1, WF1);
    xcvt_kernel<<<(N * D + 255) / 256, 256, 0, stream>>>(x, HA, N * D);

    // --- layer 0: gathers fill HA slots 1..3, then fused GEMM+bias+PReLU -> HB slot 0 ---
    gather_kernel<<<NG, 512, 0, stream>>>(HA + 0 * 64, HA + 1 * 64, rowstart, deg, epack, N);
    gather_kernel<<<NG, 512, 0, stream>>>(HA + 1 * 64, HA + 2 * 64, rowstart, deg, epack, N);
    gather_kernel<<<NG, 512, 0, stream>>>(HA + 2 * 64, HA + 3 * 64, rowstart, deg, epack, N);
    tag_gemm_kernel<2><<<NM, 256, 0, stream>>>(HA, WF0, b0, a0, nullptr, HB, nullptr, N);

    // --- layer 1: gathers fill HB slots 1..3, then fused GEMM+bias+PReLU+Wout-dot -> nscal ---
    gather_kernel<<<NG, 512, 0, stream>>>(HB + 0 * 64, HB + 1 * 64, rowstart, deg, epack, N);
    gather_kernel<<<NG, 512, 0, stream>>>(HB + 1 * 64, HB + 2 * 64, rowstart, deg, epack, N);
    gather_kernel<<<NG, 512, 0, stream>>>(HB + 2 * 64, HB + 3 * 64, rowstart, deg, epack, N);
    tag_gemm_kernel<3><<<NM, 256, 0, stream>>>(HB, WF1, b1, a1, Wout, nullptr, nscal, N);

    // --- global_add_pool (two-stage, contention-free) ---
    init_out_kernel<<<1, 128, 0, stream>>>((float*)d_out, bout, out_size);
    segsum_kernel<<<SEG_BLOCKS, 256, 0, stream>>>(nscal, batch, (float*)d_out, N);
}

// Round 7
// 332.316 us; speedup vs baseline: 1.2489x; 1.2489x over previous
//
#include <hip/hip_runtime.h>
#include <hip/hip_bf16.h>

#define D 64
#define GRAPHS 128

using bf16x8 = __attribute__((ext_vector_type(8))) short;   // 8 bf16 (4 VGPRs)
using f32x4  = __attribute__((ext_vector_type(4))) float;

// ---------------- small helpers ----------------

__device__ __forceinline__ float bf2f(unsigned short u) {
    return __uint_as_float(((unsigned)u) << 16);
}
__device__ __forceinline__ unsigned short f2bf(float f) {
    unsigned u = __float_as_uint(f);
    unsigned r = (u + 0x7FFFu + ((u >> 16) & 1u)) >> 16;   // RNE
    return (unsigned short)r;
}

// ---------------- gcn_norm / padded-CSR build ----------------
// 1 edge/thread everywhere: these kernels are latency-bound; TLP >> ILP (R6 lesson).

__global__ void deg_kernel(const int* __restrict__ dst, int* __restrict__ deg, int E) {
    int e = blockIdx.x * blockDim.x + threadIdx.x;
    if (e < E) atomicAdd(&deg[dst[e]], 1);
}

// dinv + padded degree (multiple of 8)
__global__ void dinv_kernel(const int* __restrict__ deg, float* __restrict__ dinv,
                            int* __restrict__ pdeg, int N) {
    int i = blockIdx.x * blockDim.x + threadIdx.x;
    if (i < N) {
        int d = deg[i];
        dinv[i] = d > 0 ? rsqrtf((float)d) : 0.0f;
        pdeg[i] = (d + 7) & ~7;
    }
}

__global__ void block_sum_kernel(const int* __restrict__ pdeg, int* __restrict__ bsum, int N) {
    __shared__ int s[256];
    int i = blockIdx.x * 256 + threadIdx.x;
    s[threadIdx.x] = (i < N) ? pdeg[i] : 0;
    __syncthreads();
    for (int st = 128; st > 0; st >>= 1) {
        if (threadIdx.x < st) s[threadIdx.x] += s[threadIdx.x + st];
        __syncthreads();
    }
    if (threadIdx.x == 0) bsum[blockIdx.x] = s[0];
}

__global__ void scan_bsum_kernel(const int* __restrict__ bsum, int* __restrict__ boff, int NB) {
    if (NB <= 256) {
        __shared__ int s[256];
        int i = threadIdx.x;
        int v = (i < NB) ? bsum[i] : 0;
        s[i] = v;
        __syncthreads();
        for (int st = 1; st < 256; st <<= 1) {
            int add = (i >= st) ? s[i - st] : 0;
            __syncthreads();
            s[i] += add;
            __syncthreads();
        }
        if (i < NB) boff[i] = s[i] - v;
    } else if (threadIdx.x == 0) {
        int run = 0;
        for (int i = 0; i < NB; ++i) { boff[i] = run; run += bsum[i]; }
    }
}

// scan pdeg -> rowstart/cursor; also fill pad slots [rowstart+deg, rowstart+pdeg)
// with (src=0, w=0) so the gather needs no tail handling.
__global__ void block_scan_kernel(const int* __restrict__ pdeg, const int* __restrict__ deg,
                                  const int* __restrict__ boff,
                                  int* __restrict__ rowstart, int* __restrict__ cursor,
                                  int2* __restrict__ ep, int N) {
    __shared__ int s[256];
    int i = blockIdx.x * 256 + threadIdx.x;
    int v = (i < N) ? pdeg[i] : 0;
    s[threadIdx.x] = v;
    __syncthreads();
    for (int st = 1; st < 256; st <<= 1) {
        int add = (threadIdx.x >= st) ? s[threadIdx.x - st] : 0;
        __syncthreads();
        s[threadIdx.x] += add;
        __syncthreads();
    }
    if (i < N) {
        int excl = boff[blockIdx.x] + s[threadIdx.x] - v;
        rowstart[i] = excl;
        cursor[i]   = excl;
        int d = deg[i];
        for (int p = excl + d; p < excl + v; ++p)
            ep[p] = make_int2(0, 0);                 // zero-weight pad
    }
}

__global__ void scatter_kernel(const int* __restrict__ src, const int* __restrict__ dst,
                               const float* __restrict__ dinv, int* __restrict__ cursor,
                               int2* __restrict__ ep, int E) {
    int e = blockIdx.x * blockDim.x + threadIdx.x;
    if (e < E) {
        int d = dst[e], s = src[e];
        float w = dinv[s] * dinv[d];
        int pos = atomicAdd(&cursor[d], 1);
        ep[pos] = make_int2(s, __float_as_int(w));
    }
}

// ---------------- x -> bf16 into H slot 0 ----------------

__global__ void xcvt_kernel(const float* __restrict__ x, unsigned short* __restrict__ H, int total) {
    int i = blockIdx.x * blockDim.x + threadIdx.x;
    if (i < total) {
        int n = i >> 6, f = i & 63;
        H[(size_t)n * 256 + f] = f2bf(x[i]);
    }
}

// ---------------- pure gather: out_row = sum_e w_e * in_row[src_e] ----------------
// Wave per dst node, lane = feature. Edge reads are wave-uniform (scalar pipe);
// rows padded to x8 -> every iteration is the full 8-deep pipelined body.

#define GROWS 8   // 512 threads/block

__global__ __launch_bounds__(512, 8)
void gather_kernel(const unsigned short* __restrict__ in,   // H + slot_in*64
                   unsigned short* __restrict__ out,        // H + slot_out*64
                   const int* __restrict__ rowstart, const int* __restrict__ pdeg,
                   const int2* __restrict__ ep, int N) {
    int wid = blockIdx.x * GROWS + (threadIdx.x >> 6);
    if (wid >= N) return;
    int lane = threadIdx.x & 63;

    int start = __builtin_amdgcn_readfirstlane(rowstart[wid]);
    int cnt   = __builtin_amdgcn_readfirstlane(pdeg[wid]);

    float a0 = 0.f, a1 = 0.f, a2 = 0.f, a3 = 0.f, a4 = 0.f, a5 = 0.f, a6 = 0.f, a7 = 0.f;
    for (int i = 0; i < cnt; i += 8) {
        int2 e0 = ep[start + i + 0];
        int2 e1 = ep[start + i + 1];
        int2 e2 = ep[start + i + 2];
        int2 e3 = ep[start + i + 3];
        int2 e4 = ep[start + i + 4];
        int2 e5 = ep[start + i + 5];
        int2 e6 = ep[start + i + 6];
        int2 e7 = ep[start + i + 7];
        float f0 = bf2f(in[(size_t)(unsigned)e0.x * 256 + lane]);
        float f1 = bf2f(in[(size_t)(unsigned)e1.x * 256 + lane]);
        float f2 = bf2f(in[(size_t)(unsigned)e2.x * 256 + lane]);
        float f3 = bf2f(in[(size_t)(unsigned)e3.x * 256 + lane]);
        float f4 = bf2f(in[(size_t)(unsigned)e4.x * 256 + lane]);
        float f5 = bf2f(in[(size_t)(unsigned)e5.x * 256 + lane]);
        float f6 = bf2f(in[(size_t)(unsigned)e6.x * 256 + lane]);
        float f7 = bf2f(in[(size_t)(unsigned)e7.x * 256 + lane]);
        a0 = fmaf(__int_as_float(e0.y), f0, a0);
        a1 = fmaf(__int_as_float(e1.y), f1, a1);
        a2 = fmaf(__int_as_float(e2.y), f2, a2);
        a3 = fmaf(__int_as_float(e3.y), f3, a3);
        a4 = fmaf(__int_as_float(e4.y), f4, a4);
        a5 = fmaf(__int_as_float(e5.y), f5, a5);
        a6 = fmaf(__int_as_float(e6.y), f6, a6);
        a7 = fmaf(__int_as_float(e7.y), f7, a7);
    }
    float a = ((a0 + a1) + (a2 + a3)) + ((a4 + a5) + (a6 + a7));
    out[(size_t)wid * 256 + lane] = f2bf(a);
}

// ---------------- W -> per-lane MFMA B-fragment layout (bf16), both layers ----------------
// Wfrag[kt][ct][lane][j]: B[k= kt*32 + (lane>>4)*8 + j][n= ct*16 + (lane&15)]

__global__ void wfrag_kernel(const float* __restrict__ W0, const float* __restrict__ W1,
                             unsigned short* __restrict__ WF0, unsigned short* __restrict__ WF1) {
    int idx = blockIdx.x * 256 + threadIdx.x;   // 2 * 16384
    if (idx >= 32768) return;
    int i = idx & 16383;
    int j = i & 7, lane = (i >> 3) & 63, ct = (i >> 9) & 3, kt = i >> 11;
    int n = ct * 16 + (lane & 15);
    int k = kt * 32 + (lane >> 4) * 8 + j;
    if (idx < 16384) WF0[i] = f2bf(W0[k * 64 + n]);
    else             WF1[i] = f2bf(W1[k * 64 + n]);
}

// ---------------- layer projection: C[N x 64] = H[N x 256] @ Wflat[256 x 64] ----------------

template<int MODE>
__global__ __launch_bounds__(256, 4)
void tag_gemm_kernel(const unsigned short* __restrict__ H,
                     const unsigned short* __restrict__ Wfrag,
                     const float* __restrict__ bias, const float* __restrict__ alpha,
                     const float* __restrict__ Wout,
                     unsigned short* __restrict__ H2, float* __restrict__ nscal, int N) {
    int w = threadIdx.x >> 6, lane = threadIdx.x & 63;
    int m = lane & 15, quad = lane >> 4;
    int rowbase = blockIdx.x * 64 + w * 16;
    int arow = rowbase + m;
    size_t aoff = (size_t)min(arow, N - 1) * 256 + quad * 8;

    f32x4 acc0 = {0.f, 0.f, 0.f, 0.f}, acc1 = acc0, acc2 = acc0, acc3 = acc0;
#pragma unroll
    for (int kt = 0; kt < 8; ++kt) {
        bf16x8 A = *(const bf16x8*)(H + aoff + kt * 32);
        const unsigned short* wf = Wfrag + ((size_t)(kt * 4) * 64 + lane) * 8;
        bf16x8 B0 = *(const bf16x8*)(wf + 0 * 64 * 8);
        bf16x8 B1 = *(const bf16x8*)(wf + 1 * 64 * 8);
        bf16x8 B2 = *(const bf16x8*)(wf + 2 * 64 * 8);
        bf16x8 B3 = *(const bf16x8*)(wf + 3 * 64 * 8);
        acc0 = __builtin_amdgcn_mfma_f32_16x16x32_bf16(A, B0, acc0, 0, 0, 0);
        acc1 = __builtin_amdgcn_mfma_f32_16x16x32_bf16(A, B1, acc1, 0, 0, 0);
        acc2 = __builtin_amdgcn_mfma_f32_16x16x32_bf16(A, B2, acc2, 0, 0, 0);
        acc3 = __builtin_amdgcn_mfma_f32_16x16x32_bf16(A, B3, acc3, 0, 0, 0);
    }

    float al = alpha[0];
    f32x4 accs[4] = {acc0, acc1, acc2, acc3};
    if (MODE == 2) {
#pragma unroll
        for (int ct = 0; ct < 4; ++ct) {
            int col = ct * 16 + m;
            float b = bias[col];
#pragma unroll
            for (int r = 0; r < 4; ++r) {
                int row = rowbase + quad * 4 + r;
                if (row < N) {
                    float v = accs[ct][r] + b;
                    v = v >= 0.f ? v : al * v;
                    H2[(size_t)row * 256 + col] = f2bf(v);
                }
            }
        }
    } else {
        float rv0 = 0.f, rv1 = 0.f, rv2 = 0.f, rv3 = 0.f;
#pragma unroll
        for (int ct = 0; ct < 4; ++ct) {
            int col = ct * 16 + m;
            float b = bias[col], wo = Wout[col];
            float v;
            v = accs[ct][0] + b; v = v >= 0.f ? v : al * v; rv0 = fmaf(v, wo, rv0);
            v = accs[ct][1] + b; v = v >= 0.f ? v : al * v; rv1 = fmaf(v, wo, rv1);
            v = accs[ct][2] + b; v = v >= 0.f ? v : al * v; rv2 = fmaf(v, wo, rv2);
            v = accs[ct][3] + b; v = v >= 0.f ? v : al * v; rv3 = fmaf(v, wo, rv3);
        }
        float rv[4] = {rv0, rv1, rv2, rv3};
#pragma unroll
        for (int r = 0; r < 4; ++r) {
            float v = rv[r];
            v += __shfl_xor(v, 8, 16);
            v += __shfl_xor(v, 4, 16);
            v += __shfl_xor(v, 2, 16);
            v += __shfl_xor(v, 1, 16);
            int row = rowbase + quad * 4 + r;
            if (m == 0 && row < N) nscal[row] = v;
        }
    }
}

// ---------------- atomic-free segment-sum: batch is sorted -> block per graph ----------------

__global__ void segsum_kernel(const float* __restrict__ s, const int* __restrict__ batch,
                              const float* __restrict__ bout, float* __restrict__ out, int N) {
    int g = blockIdx.x;
    // lower_bound(batch, g) and lower_bound(batch, g+1)
    int lo = 0, hi = N;
    while (lo < hi) { int mid = (lo + hi) >> 1; if (batch[mid] < g) lo = mid + 1; else hi = mid; }
    int lo2 = lo, hi2 = N;
    while (lo2 < hi2) { int mid = (lo2 + hi2) >> 1; if (batch[mid] < g + 1) lo2 = mid + 1; else hi2 = mid; }

    float v = 0.0f;
    for (int i = lo + threadIdx.x; i < lo2; i += 256) v += s[i];
    __shared__ float red[256];
    red[threadIdx.x] = v;
    __syncthreads();
    for (int st = 128; st > 0; st >>= 1) {
        if (threadIdx.x < st) red[threadIdx.x] += red[threadIdx.x + st];
        __syncthreads();
    }
    if (threadIdx.x == 0) out[g] = red[0] + bout[0];
}

extern "C" void kernel_launch(void* const* d_in, const int* in_sizes, int n_in,
                              void* d_out, int out_size, void* d_ws, size_t ws_size,
                              hipStream_t stream) {
    const float* x     = (const float*)d_in[0];
    const int*   ei    = (const int*)d_in[1];
    const int*   batch = (const int*)d_in[2];
    const float* W0    = (const float*)d_in[3];
    const float* b0    = (const float*)d_in[4];
    const float* W1    = (const float*)d_in[5];
    const float* b1    = (const float*)d_in[6];
    const float* a0    = (const float*)d_in[7];
    const float* a1    = (const float*)d_in[8];
    const float* Wout  = (const float*)d_in[9];
    const float* bout  = (const float*)d_in[10];

    const int N = in_sizes[0] / D;
    const int E = in_sizes[1] / 2;
    const int* src = ei;
    const int* dst = ei + E;

    size_t off = 0;
    auto alloc = [&](size_t bytes) -> void* {
        void* p = (char*)d_ws + off;
        off = (off + bytes + 255) & ~(size_t)255;
        return p;
    };
    const int NB = (N + 255) / 256;
    int*   deg      = (int*)alloc((size_t)N * 4);
    int*   pdeg     = (int*)alloc((size_t)N * 4);
    int*   rowstart = (int*)alloc((size_t)N * 4);
    int*   cursor   = (int*)alloc((size_t)N * 4);
    float* dinv     = (float*)alloc((size_t)N * 4);
    int*   bsum     = (int*)alloc((size_t)NB * 4);
    int*   boff     = (int*)alloc((size_t)NB * 4);
    int2*  epack    = (int2*)alloc(((size_t)E + 8ull * N) * 8);        // padded CSR
    unsigned short* HA = (unsigned short*)alloc((size_t)N * 256 * 2);  // [N][4][64] bf16
    unsigned short* HB = (unsigned short*)alloc((size_t)N * 256 * 2);
    unsigned short* WF0 = (unsigned short*)alloc(16384 * 2);
    unsigned short* WF1 = (unsigned short*)alloc(16384 * 2);
    float* nscal    = (float*)alloc((size_t)N * 4);

    const int EB = (E + 255) / 256;
    const int NG = (N + GROWS - 1) / GROWS;      // gather blocks (512 thr)
    const int NM = (N + 63) / 64;                // gemm blocks (256 thr)

    // --- gcn_norm + padded-CSR build + weight/x prep ---
    hipMemsetAsync(deg, 0, (size_t)N * 4, stream);
    deg_kernel<<<EB, 256, 0, stream>>>(dst, deg, E);
    dinv_kernel<<<NB, 256, 0, stream>>>(deg, dinv, pdeg, N);
    block_sum_kernel<<<NB, 256, 0, stream>>>(pdeg, bsum, N);
    scan_bsum_kernel<<<1, 256, 0, stream>>>(bsum, boff, NB);
    block_scan_kernel<<<NB, 256, 0, stream>>>(pdeg, deg, boff, rowstart, cursor, epack, N);
    scatter_kernel<<<EB, 256, 0, stream>>>(src, dst, dinv, cursor, epack, E);
    wfrag_kernel<<<128, 256, 0, stream>>>(W0, W1, WF0, WF1);
    xcvt_kernel<<<(N * D + 255) / 256, 256, 0, stream>>>(x, HA, N * D);

    // --- layer 0: gathers fill HA slots 1..3, then fused GEMM+bias+PReLU -> HB slot 0 ---
    gather_kernel<<<NG, 512, 0, stream>>>(HA + 0 * 64, HA + 1 * 64, rowstart, pdeg, epack, N);
    gather_kernel<<<NG, 512, 0, stream>>>(HA + 1 * 64, HA + 2 * 64, rowstart, pdeg, epack, N);
    gather_kernel<<<NG, 512, 0, stream>>>(HA + 2 * 64, HA + 3 * 64, rowstart, pdeg, epack, N);
    tag_gemm_kernel<2><<<NM, 256, 0, stream>>>(HA, WF0, b0, a0, nullptr, HB, nullptr, N);

    // --- layer 1: gathers fill HB slots 1..3, then fused GEMM+bias+PReLU+Wout-dot -> nscal ---
    gather_kernel<<<NG, 512, 0, stream>>>(HB + 0 * 64, HB + 1 * 64, rowstart, pdeg, epack, N);
    gather_kernel<<<NG, 512, 0, stream>>>(HB + 1 * 64, HB + 2 * 64, rowstart, pdeg, epack, N);
    gather_kernel<<<NG, 512, 0, stream>>>(HB + 2 * 64, HB + 3 * 64, rowstart, pdeg, epack, N);
    tag_gemm_kernel<3><<<NM, 256, 0, stream>>>(HB, WF1, b1, a1, Wout, nullptr, nscal, N);

    // --- global_add_pool: block per graph, atomic-free (batch sorted) ---
    segsum_kernel<<<GRAPHS, 256, 0, stream>>>(nscal, batch, bout, (float*)d_out, N);
}

// Round 8
// 317.284 us; speedup vs baseline: 1.3081x; 1.0474x over previous
//
#include <hip/hip_runtime.h>
#include <hip/hip_bf16.h>

#define D 64
#define GRAPHS 128

using bf16x8 = __attribute__((ext_vector_type(8))) short;   // 8 bf16 (4 VGPRs)
using f32x4  = __attribute__((ext_vector_type(4))) float;

// ---------------- small helpers ----------------

__device__ __forceinline__ float bf2f(unsigned short u) {
    return __uint_as_float(((unsigned)u) << 16);
}
__device__ __forceinline__ unsigned short f2bf(float f) {
    unsigned u = __float_as_uint(f);
    unsigned r = (u + 0x7FFFu + ((u >> 16) & 1u)) >> 16;   // RNE
    return (unsigned short)r;
}

// ---------------- gcn_norm / padded-CSR build (atomic chain only in deg pass) ----------------

// record each edge's slot within its dst row: pos[e] = old count (coalesced write)
__global__ void deg_kernel(const int* __restrict__ dst, int* __restrict__ deg,
                           int* __restrict__ pos, int E) {
    int e = blockIdx.x * blockDim.x + threadIdx.x;
    if (e < E) pos[e] = atomicAdd(&deg[dst[e]], 1);
}

// dinv + padded degree + block partial-sum, one launch
__global__ void dinv_bsum_kernel(const int* __restrict__ deg, float* __restrict__ dinv,
                                 int* __restrict__ pdeg, int* __restrict__ bsum, int N) {
    __shared__ int s[256];
    int i = blockIdx.x * 256 + threadIdx.x;
    int p = 0;
    if (i < N) {
        int d = deg[i];
        dinv[i] = d > 0 ? rsqrtf((float)d) : 0.0f;
        p = (d + 7) & ~7;
        pdeg[i] = p;
    }
    s[threadIdx.x] = p;
    __syncthreads();
    for (int st = 128; st > 0; st >>= 1) {
        if (threadIdx.x < st) s[threadIdx.x] += s[threadIdx.x + st];
        __syncthreads();
    }
    if (threadIdx.x == 0) bsum[blockIdx.x] = s[0];
}

__global__ void scan_bsum_kernel(const int* __restrict__ bsum, int* __restrict__ boff, int NB) {
    if (NB <= 256) {
        __shared__ int s[256];
        int i = threadIdx.x;
        int v = (i < NB) ? bsum[i] : 0;
        s[i] = v;
        __syncthreads();
        for (int st = 1; st < 256; st <<= 1) {
            int add = (i >= st) ? s[i - st] : 0;
            __syncthreads();
            s[i] += add;
            __syncthreads();
        }
        if (i < NB) boff[i] = s[i] - v;
    } else if (threadIdx.x == 0) {
        int run = 0;
        for (int i = 0; i < NB; ++i) { boff[i] = run; run += bsum[i]; }
    }
}

// scan pdeg -> rowstart; fill pad slots [rowstart+deg, rowstart+pdeg) with (src=0, w=0)
__global__ void block_scan_kernel(const int* __restrict__ pdeg, const int* __restrict__ deg,
                                  const int* __restrict__ boff,
                                  int* __restrict__ rowstart, int2* __restrict__ ep, int N) {
    __shared__ int s[256];
    int i = blockIdx.x * 256 + threadIdx.x;
    int v = (i < N) ? pdeg[i] : 0;
    s[threadIdx.x] = v;
    __syncthreads();
    for (int st = 1; st < 256; st <<= 1) {
        int add = (threadIdx.x >= st) ? s[threadIdx.x - st] : 0;
        __syncthreads();
        s[threadIdx.x] += add;
        __syncthreads();
    }
    if (i < N) {
        int excl = boff[blockIdx.x] + s[threadIdx.x] - v;
        rowstart[i] = excl;
        int d = deg[i];
        for (int p = excl + d; p < excl + v; ++p)
            ep[p] = make_int2(0, 0);                 // zero-weight pad
    }
}

// atomic-free scatter: slot comes from pos[e]
__global__ void scatter_kernel(const int* __restrict__ src, const int* __restrict__ dst,
                               const int* __restrict__ pos, const float* __restrict__ dinv,
                               const int* __restrict__ rowstart, int2* __restrict__ ep, int E) {
    int e = blockIdx.x * blockDim.x + threadIdx.x;
    if (e < E) {
        int d = dst[e], s = src[e];
        float w = dinv[s] * dinv[d];
        ep[rowstart[d] + pos[e]] = make_int2(s, __float_as_int(w));
    }
}

// ---------------- prep: W -> MFMA B-fragments (both layers) + x -> bf16 slot 0 ----------------
// Wfrag[kt][ct][lane][j]: B[k= kt*32 + (lane>>4)*8 + j][n= ct*16 + (lane&15)]

__global__ void prep_kernel(const float* __restrict__ W0, const float* __restrict__ W1,
                            unsigned short* __restrict__ WF0, unsigned short* __restrict__ WF1,
                            const float* __restrict__ x, unsigned short* __restrict__ H, int total) {
    int b = blockIdx.x;
    if (b < 128) {
        int idx = b * 256 + threadIdx.x;   // 32768 = 2 * 16384
        int i = idx & 16383;
        int j = i & 7, lane = (i >> 3) & 63, ct = (i >> 9) & 3, kt = i >> 11;
        int n = ct * 16 + (lane & 15);
        int k = kt * 32 + (lane >> 4) * 8 + j;
        if (idx < 16384) WF0[i] = f2bf(W0[k * 64 + n]);
        else             WF1[i] = f2bf(W1[k * 64 + n]);
    } else {
        int i = (b - 128) * 256 + threadIdx.x;
        if (i < total) {
            int n = i >> 6, f = i & 63;
            H[(size_t)n * 256 + f] = f2bf(x[i]);
        }
    }
}

// ---------------- pure gather: out_row = sum_e w_e * in_row[src_e] ----------------
// Wave per dst node. 16 lanes per edge: group g=lane>>4 owns edge i+g; each lane
// loads ushort4 (4 features, 8 B). One VMEM instruction covers 4 edges' rows
// (4 x 128 B coalesced segments); ep loads of 4 consecutive edges coalesce to
// one 32 B txn. 8 edges in flight per iteration; 2 shfl_xor to combine groups.

#define GROWS 8   // 512 threads/block, 8 nodes/block

__global__ __launch_bounds__(512, 8)
void gather_kernel(const unsigned short* __restrict__ in,   // H + slot_in*64
                   unsigned short* __restrict__ out,        // H + slot_out*64
                   const int* __restrict__ rowstart, const int* __restrict__ pdeg,
                   const int2* __restrict__ ep, int N) {
    int wid = blockIdx.x * GROWS + (threadIdx.x >> 6);
    if (wid >= N) return;
    int lane = threadIdx.x & 63;
    int g  = lane >> 4;          // edge subgroup 0..3
    int fl = (lane & 15) * 4;    // feature base (4 features per lane)

    int start = __builtin_amdgcn_readfirstlane(rowstart[wid]);
    int cnt   = __builtin_amdgcn_readfirstlane(pdeg[wid]);    // multiple of 8

    float a0 = 0.f, a1 = 0.f, a2 = 0.f, a3 = 0.f;
    float b0 = 0.f, b1 = 0.f, b2 = 0.f, b3 = 0.f;
    for (int i = 0; i < cnt; i += 8) {
        int2 eA = ep[start + i + g];
        int2 eB = ep[start + i + 4 + g];
        ushort4 rA = *(const ushort4*)(in + (size_t)(unsigned)eA.x * 256 + fl);
        ushort4 rB = *(const ushort4*)(in + (size_t)(unsigned)eB.x * 256 + fl);
        float wA = __int_as_float(eA.y), wB = __int_as_float(eB.y);
        a0 = fmaf(wA, bf2f(rA.x), a0);
        a1 = fmaf(wA, bf2f(rA.y), a1);
        a2 = fmaf(wA, bf2f(rA.z), a2);
        a3 = fmaf(wA, bf2f(rA.w), a3);
        b0 = fmaf(wB, bf2f(rB.x), b0);
        b1 = fmaf(wB, bf2f(rB.y), b1);
        b2 = fmaf(wB, bf2f(rB.z), b2);
        b3 = fmaf(wB, bf2f(rB.w), b3);
    }
    a0 += b0; a1 += b1; a2 += b2; a3 += b3;
    // combine the 4 edge-subgroups (same features, different edges)
    a0 += __shfl_xor(a0, 16, 64); a0 += __shfl_xor(a0, 32, 64);
    a1 += __shfl_xor(a1, 16, 64); a1 += __shfl_xor(a1, 32, 64);
    a2 += __shfl_xor(a2, 16, 64); a2 += __shfl_xor(a2, 32, 64);
    a3 += __shfl_xor(a3, 16, 64); a3 += __shfl_xor(a3, 32, 64);
    if (g == 0) {
        ushort4 pk;
        pk.x = f2bf(a0); pk.y = f2bf(a1); pk.z = f2bf(a2); pk.w = f2bf(a3);
        *(ushort4*)(out + (size_t)wid * 256 + fl) = pk;   // 16 lanes x 8 B = full row
    }
}

// ---------------- layer projection: C[N x 64] = H[N x 256] @ Wflat[256 x 64] ----------------

template<int MODE>
__global__ __launch_bounds__(256, 4)
void tag_gemm_kernel(const unsigned short* __restrict__ H,
                     const unsigned short* __restrict__ Wfrag,
                     const float* __restrict__ bias, const float* __restrict__ alpha,
                     const float* __restrict__ Wout,
                     unsigned short* __restrict__ H2, float* __restrict__ nscal, int N) {
    int w = threadIdx.x >> 6, lane = threadIdx.x & 63;
    int m = lane & 15, quad = lane >> 4;
    int rowbase = blockIdx.x * 64 + w * 16;
    int arow = rowbase + m;
    size_t aoff = (size_t)min(arow, N - 1) * 256 + quad * 8;

    f32x4 acc0 = {0.f, 0.f, 0.f, 0.f}, acc1 = acc0, acc2 = acc0, acc3 = acc0;
#pragma unroll
    for (int kt = 0; kt < 8; ++kt) {
        bf16x8 A = *(const bf16x8*)(H + aoff + kt * 32);
        const unsigned short* wf = Wfrag + ((size_t)(kt * 4) * 64 + lane) * 8;
        bf16x8 B0 = *(const bf16x8*)(wf + 0 * 64 * 8);
        bf16x8 B1 = *(const bf16x8*)(wf + 1 * 64 * 8);
        bf16x8 B2 = *(const bf16x8*)(wf + 2 * 64 * 8);
        bf16x8 B3 = *(const bf16x8*)(wf + 3 * 64 * 8);
        acc0 = __builtin_amdgcn_mfma_f32_16x16x32_bf16(A, B0, acc0, 0, 0, 0);
        acc1 = __builtin_amdgcn_mfma_f32_16x16x32_bf16(A, B1, acc1, 0, 0, 0);
        acc2 = __builtin_amdgcn_mfma_f32_16x16x32_bf16(A, B2, acc2, 0, 0, 0);
        acc3 = __builtin_amdgcn_mfma_f32_16x16x32_bf16(A, B3, acc3, 0, 0, 0);
    }

    float al = alpha[0];
    f32x4 accs[4] = {acc0, acc1, acc2, acc3};
    if (MODE == 2) {
#pragma unroll
        for (int ct = 0; ct < 4; ++ct) {
            int col = ct * 16 + m;
            float b = bias[col];
#pragma unroll
            for (int r = 0; r < 4; ++r) {
                int row = rowbase + quad * 4 + r;
                if (row < N) {
                    float v = accs[ct][r] + b;
                    v = v >= 0.f ? v : al * v;
                    H2[(size_t)row * 256 + col] = f2bf(v);
                }
            }
        }
    } else {
        float rv0 = 0.f, rv1 = 0.f, rv2 = 0.f, rv3 = 0.f;
#pragma unroll
        for (int ct = 0; ct < 4; ++ct) {
            int col = ct * 16 + m;
            float b = bias[col], wo = Wout[col];
            float v;
            v = accs[ct][0] + b; v = v >= 0.f ? v : al * v; rv0 = fmaf(v, wo, rv0);
            v = accs[ct][1] + b; v = v >= 0.f ? v : al * v; rv1 = fmaf(v, wo, rv1);
            v = accs[ct][2] + b; v = v >= 0.f ? v : al * v; rv2 = fmaf(v, wo, rv2);
            v = accs[ct][3] + b; v = v >= 0.f ? v : al * v; rv3 = fmaf(v, wo, rv3);
        }
        float rv[4] = {rv0, rv1, rv2, rv3};
#pragma unroll
        for (int r = 0; r < 4; ++r) {
            float v = rv[r];
            v += __shfl_xor(v, 8, 16);
            v += __shfl_xor(v, 4, 16);
            v += __shfl_xor(v, 2, 16);
            v += __shfl_xor(v, 1, 16);
            int row = rowbase + quad * 4 + r;
            if (m == 0 && row < N) nscal[row] = v;
        }
    }
}

// ---------------- atomic-free segment-sum: batch is sorted -> block per graph ----------------

__global__ void segsum_kernel(const float* __restrict__ s, const int* __restrict__ batch,
                              const float* __restrict__ bout, float* __restrict__ out, int N) {
    int g = blockIdx.x;
    int lo = 0, hi = N;
    while (lo < hi) { int mid = (lo + hi) >> 1; if (batch[mid] < g) lo = mid + 1; else hi = mid; }
    int lo2 = lo, hi2 = N;
    while (lo2 < hi2) { int mid = (lo2 + hi2) >> 1; if (batch[mid] < g + 1) lo2 = mid + 1; else hi2 = mid; }

    float v = 0.0f;
    for (int i = lo + threadIdx.x; i < lo2; i += 256) v += s[i];
    __shared__ float red[256];
    red[threadIdx.x] = v;
    __syncthreads();
    for (int st = 128; st > 0; st >>= 1) {
        if (threadIdx.x < st) red[threadIdx.x] += red[threadIdx.x + st];
        __syncthreads();
    }
    if (threadIdx.x == 0) out[g] = red[0] + bout[0];
}

extern "C" void kernel_launch(void* const* d_in, const int* in_sizes, int n_in,
                              void* d_out, int out_size, void* d_ws, size_t ws_size,
                              hipStream_t stream) {
    const float* x     = (const float*)d_in[0];
    const int*   ei    = (const int*)d_in[1];
    const int*   batch = (const int*)d_in[2];
    const float* W0    = (const float*)d_in[3];
    const float* b0    = (const float*)d_in[4];
    const float* W1    = (const float*)d_in[5];
    const float* b1    = (const float*)d_in[6];
    const float* a0    = (const float*)d_in[7];
    const float* a1    = (const float*)d_in[8];
    const float* Wout  = (const float*)d_in[9];
    const float* bout  = (const float*)d_in[10];

    const int N = in_sizes[0] / D;
    const int E = in_sizes[1] / 2;
    const int* src = ei;
    const int* dst = ei + E;

    size_t off = 0;
    auto alloc = [&](size_t bytes) -> void* {
        void* p = (char*)d_ws + off;
        off = (off + bytes + 255) & ~(size_t)255;
        return p;
    };
    const int NB = (N + 255) / 256;
    int*   deg      = (int*)alloc((size_t)N * 4);
    int*   pdeg     = (int*)alloc((size_t)N * 4);
    int*   rowstart = (int*)alloc((size_t)N * 4);
    float* dinv     = (float*)alloc((size_t)N * 4);
    int*   pos      = (int*)alloc((size_t)E * 4);
    int*   bsum     = (int*)alloc((size_t)NB * 4);
    int*   boff     = (int*)alloc((size_t)NB * 4);
    int2*  epack    = (int2*)alloc(((size_t)E + 8ull * N) * 8);        // padded CSR
    unsigned short* HA = (unsigned short*)alloc((size_t)N * 256 * 2);  // [N][4][64] bf16
    unsigned short* HB = (unsigned short*)alloc((size_t)N * 256 * 2);
    unsigned short* WF0 = (unsigned short*)alloc(16384 * 2);
    unsigned short* WF1 = (unsigned short*)alloc(16384 * 2);
    float* nscal    = (float*)alloc((size_t)N * 4);

    const int EB = (E + 255) / 256;
    const int NG = (N + GROWS - 1) / GROWS;      // gather blocks (512 thr)
    const int NM = (N + 63) / 64;                // gemm blocks (256 thr)
    const int NT = (N * D + 255) / 256;          // xcvt blocks

    // --- gcn_norm + padded-CSR build + weight/x prep ---
    hipMemsetAsync(deg, 0, (size_t)N * 4, stream);
    deg_kernel<<<EB, 256, 0, stream>>>(dst, deg, pos, E);
    dinv_bsum_kernel<<<NB, 256, 0, stream>>>(deg, dinv, pdeg, bsum, N);
    scan_bsum_kernel<<<1, 256, 0, stream>>>(bsum, boff, NB);
    block_scan_kernel<<<NB, 256, 0, stream>>>(pdeg, deg, boff, rowstart, epack, N);
    scatter_kernel<<<EB, 256, 0, stream>>>(src, dst, pos, dinv, rowstart, epack, E);
    prep_kernel<<<128 + NT, 256, 0, stream>>>(W0, W1, WF0, WF1, x, HA, N * D);

    // --- layer 0: gathers fill HA slots 1..3, then fused GEMM+bias+PReLU -> HB slot 0 ---
    gather_kernel<<<NG, 512, 0, stream>>>(HA + 0 * 64, HA + 1 * 64, rowstart, pdeg, epack, N);
    gather_kernel<<<NG, 512, 0, stream>>>(HA + 1 * 64, HA + 2 * 64, rowstart, pdeg, epack, N);
    gather_kernel<<<NG, 512, 0, stream>>>(HA + 2 * 64, HA + 3 * 64, rowstart, pdeg, epack, N);
    tag_gemm_kernel<2><<<NM, 256, 0, stream>>>(HA, WF0, b0, a0, nullptr, HB, nullptr, N);

    // --- layer 1: gathers fill HB slots 1..3, then fused GEMM+bias+PReLU+Wout-dot -> nscal ---
    gather_kernel<<<NG, 512, 0, stream>>>(HB + 0 * 64, HB + 1 * 64, rowstart, pdeg, epack, N);
    gather_kernel<<<NG, 512, 0, stream>>>(HB + 1 * 64, HB + 2 * 64, rowstart, pdeg, epack, N);
    gather_kernel<<<NG, 512, 0, stream>>>(HB + 2 * 64, HB + 3 * 64, rowstart, pdeg, epack, N);
    tag_gemm_kernel<3><<<NM, 256, 0, stream>>>(HB, WF1, b1, a1, Wout, nullptr, nscal, N);

    // --- global_add_pool: block per graph, atomic-free (batch sorted) ---
    segsum_kernel<<<GRAPHS, 256, 0, stream>>>(nscal, batch, bout, (float*)d_out, N);
}

// Round 9
// 281.119 us; speedup vs baseline: 1.4763x; 1.1286x over previous
//
#include <hip/hip_runtime.h>
#include <hip/hip_bf16.h>
#include <hip/hip_fp16.h>

#define D 64
#define GRAPHS 128

using bf16x8 = __attribute__((ext_vector_type(8))) short;   // 8 bf16 (4 VGPRs)
using f32x4  = __attribute__((ext_vector_type(4))) float;

// ---------------- small helpers ----------------

__device__ __forceinline__ float bf2f(unsigned short u) {
    return __uint_as_float(((unsigned)u) << 16);
}
__device__ __forceinline__ unsigned short f2bf(float f) {
    unsigned u = __float_as_uint(f);
    unsigned r = (u + 0x7FFFu + ((u >> 16) & 1u)) >> 16;   // RNE
    return (unsigned short)r;
}

// ---------------- pass 1: degree histogram + slot record, fused with W/x prep ----------------
// ep entry = (src u16) | (fp16(dinv[src]) << 16)  -- dinv[dst] factored out (applied in gather).

__global__ void deg_prep_kernel(const int* __restrict__ dst, int* __restrict__ deg,
                                int* __restrict__ pos, int E, int EB,
                                const float* __restrict__ W0, const float* __restrict__ W1,
                                unsigned short* __restrict__ WF0, unsigned short* __restrict__ WF1,
                                const float* __restrict__ x, unsigned short* __restrict__ H, int total) {
    int b = blockIdx.x;
    if (b < EB) {
        int e = b * 256 + threadIdx.x;
        if (e < E) pos[e] = atomicAdd(&deg[dst[e]], 1);
    } else if (b < EB + 128) {
        // Wfrag[kt][ct][lane][j]: B[k= kt*32 + (lane>>4)*8 + j][n= ct*16 + (lane&15)]
        int idx = (b - EB) * 256 + threadIdx.x;   // 32768 = 2 * 16384
        int i = idx & 16383;
        int j = i & 7, lane = (i >> 3) & 63, ct = (i >> 9) & 3, kt = i >> 11;
        int n = ct * 16 + (lane & 15);
        int k = kt * 32 + (lane >> 4) * 8 + j;
        if (idx < 16384) WF0[i] = f2bf(W0[k * 64 + n]);
        else             WF1[i] = f2bf(W1[k * 64 + n]);
    } else {
        int i = (b - EB - 128) * 256 + threadIdx.x;
        if (i < total) {
            int n = i >> 6, f = i & 63;
            H[(size_t)n * 256 + f] = f2bf(x[i]);
        }
    }
}

// ---------------- pass 2: dinv + pdeg + single-pass scan (atomic block ticket) + pad fill ----------------
// CSR row placement order is block-arbitrary but consistent within a replay -- harmless.

__global__ void scan_all_kernel(const int* __restrict__ deg, float* __restrict__ dinv,
                                int* __restrict__ pdeg, int* __restrict__ rowstart,
                                unsigned int* __restrict__ ep, int* __restrict__ total, int N) {
    __shared__ int s[256];
    __shared__ int base_sh;
    int i = blockIdx.x * 256 + threadIdx.x;
    int d = 0, p = 0;
    if (i < N) {
        d = deg[i];
        dinv[i] = d > 0 ? rsqrtf((float)d) : 0.0f;
        p = (d + 7) & ~7;
        pdeg[i] = p;
    }
    s[threadIdx.x] = p;
    __syncthreads();
    for (int st = 1; st < 256; st <<= 1) {
        int add = (threadIdx.x >= st) ? s[threadIdx.x - st] : 0;
        __syncthreads();
        s[threadIdx.x] += add;
        __syncthreads();
    }
    if (threadIdx.x == 255) base_sh = atomicAdd(total, s[255]);
    __syncthreads();
    if (i < N) {
        int excl = base_sh + s[threadIdx.x] - p;
        rowstart[i] = excl;
        for (int q = excl + d; q < excl + p; ++q) ep[q] = 0u;   // zero-weight pad
    }
}

// ---------------- pass 3: atomic-free scatter into padded CSR ----------------

__global__ void scatter_kernel(const int* __restrict__ src, const int* __restrict__ dst,
                               const int* __restrict__ pos, const float* __restrict__ dinv,
                               const int* __restrict__ rowstart, unsigned int* __restrict__ ep, int E) {
    int e = blockIdx.x * blockDim.x + threadIdx.x;
    if (e < E) {
        int d = dst[e], s = src[e];
        unsigned short wu = __half_as_ushort(__float2half(dinv[s]));
        ep[rowstart[d] + pos[e]] = (unsigned)s | ((unsigned)wu << 16);
    }
}

// ---------------- pure gather: out_row = dinv[dst] * sum_e dinv[src_e] * in_row[src_e] ----------------
// Wave per dst node. 16 lanes per edge (ushort4 = 4 features/lane); ep entries 4 B;
// next iteration's ep words prefetched before current row FMAs (hides ep->row chain).

#define GROWS 8   // 512 threads/block, 8 nodes/block

__global__ __launch_bounds__(512, 8)
void gather_kernel(const unsigned short* __restrict__ in,   // H + slot_in*64
                   unsigned short* __restrict__ out,        // H + slot_out*64
                   const int* __restrict__ rowstart, const int* __restrict__ pdeg,
                   const float* __restrict__ dinv, const unsigned int* __restrict__ ep, int N) {
    int wid = blockIdx.x * GROWS + (threadIdx.x >> 6);
    if (wid >= N) return;
    int lane = threadIdx.x & 63;
    int g  = lane >> 4;          // edge subgroup 0..3
    int fl = (lane & 15) * 4;    // feature base (4 features per lane)

    int start = __builtin_amdgcn_readfirstlane(rowstart[wid]);
    int cnt   = __builtin_amdgcn_readfirstlane(pdeg[wid]);    // multiple of 8
    float dd  = dinv[wid];                                    // wave-uniform

    float a0 = 0.f, a1 = 0.f, a2 = 0.f, a3 = 0.f;
    float b0 = 0.f, b1 = 0.f, b2 = 0.f, b3 = 0.f;
    unsigned eA = 0, eB = 0;
    if (cnt > 0) { eA = ep[start + g]; eB = ep[start + 4 + g]; }
    for (int i = 0; i < cnt; i += 8) {
        unsigned cA = eA, cB = eB;
        if (i + 8 < cnt) { eA = ep[start + i + 8 + g]; eB = ep[start + i + 12 + g]; }
        ushort4 rA = *(const ushort4*)(in + (size_t)(cA & 0xFFFFu) * 256 + fl);
        ushort4 rB = *(const ushort4*)(in + (size_t)(cB & 0xFFFFu) * 256 + fl);
        float wA = __half2float(__ushort_as_half((unsigned short)(cA >> 16)));
        float wB = __half2float(__ushort_as_half((unsigned short)(cB >> 16)));
        a0 = fmaf(wA, bf2f(rA.x), a0);
        a1 = fmaf(wA, bf2f(rA.y), a1);
        a2 = fmaf(wA, bf2f(rA.z), a2);
        a3 = fmaf(wA, bf2f(rA.w), a3);
        b0 = fmaf(wB, bf2f(rB.x), b0);
        b1 = fmaf(wB, bf2f(rB.y), b1);
        b2 = fmaf(wB, bf2f(rB.z), b2);
        b3 = fmaf(wB, bf2f(rB.w), b3);
    }
    a0 += b0; a1 += b1; a2 += b2; a3 += b3;
    a0 += __shfl_xor(a0, 16, 64); a0 += __shfl_xor(a0, 32, 64);
    a1 += __shfl_xor(a1, 16, 64); a1 += __shfl_xor(a1, 32, 64);
    a2 += __shfl_xor(a2, 16, 64); a2 += __shfl_xor(a2, 32, 64);
    a3 += __shfl_xor(a3, 16, 64); a3 += __shfl_xor(a3, 32, 64);
    if (g == 0) {
        ushort4 pk;
        pk.x = f2bf(a0 * dd); pk.y = f2bf(a1 * dd); pk.z = f2bf(a2 * dd); pk.w = f2bf(a3 * dd);
        *(ushort4*)(out + (size_t)wid * 256 + fl) = pk;
    }
}

// ---------------- layer projection: C[N x 64] = H[N x 256] @ Wflat[256 x 64] ----------------
// MODE 2: H2 = prelu(C+b) (bf16); also block 0 initializes out[] = bout.
// MODE 3: pool fused: LDS bins per block (batch sorted -> ~2 graphs/block), few global atomics.

template<int MODE>
__global__ __launch_bounds__(256, 4)
void tag_gemm_kernel(const unsigned short* __restrict__ H,
                     const unsigned short* __restrict__ Wfrag,
                     const float* __restrict__ bias, const float* __restrict__ alpha,
                     const float* __restrict__ Wout, const int* __restrict__ batch,
                     const float* __restrict__ bout,
                     unsigned short* __restrict__ H2, float* __restrict__ outp, int N) {
    __shared__ float bins[GRAPHS];
    if (MODE == 3) {
        if (threadIdx.x < GRAPHS) bins[threadIdx.x] = 0.0f;
        __syncthreads();
    }
    if (MODE == 2) {
        if (blockIdx.x == 0 && threadIdx.x < GRAPHS) outp[threadIdx.x] = bout[0];
    }

    int w = threadIdx.x >> 6, lane = threadIdx.x & 63;
    int m = lane & 15, quad = lane >> 4;
    int rowbase = blockIdx.x * 64 + w * 16;
    int arow = rowbase + m;
    size_t aoff = (size_t)min(arow, N - 1) * 256 + quad * 8;

    f32x4 acc0 = {0.f, 0.f, 0.f, 0.f}, acc1 = acc0, acc2 = acc0, acc3 = acc0;
#pragma unroll
    for (int kt = 0; kt < 8; ++kt) {
        bf16x8 A = *(const bf16x8*)(H + aoff + kt * 32);
        const unsigned short* wf = Wfrag + ((size_t)(kt * 4) * 64 + lane) * 8;
        bf16x8 B0 = *(const bf16x8*)(wf + 0 * 64 * 8);
        bf16x8 B1 = *(const bf16x8*)(wf + 1 * 64 * 8);
        bf16x8 B2 = *(const bf16x8*)(wf + 2 * 64 * 8);
        bf16x8 B3 = *(const bf16x8*)(wf + 3 * 64 * 8);
        acc0 = __builtin_amdgcn_mfma_f32_16x16x32_bf16(A, B0, acc0, 0, 0, 0);
        acc1 = __builtin_amdgcn_mfma_f32_16x16x32_bf16(A, B1, acc1, 0, 0, 0);
        acc2 = __builtin_amdgcn_mfma_f32_16x16x32_bf16(A, B2, acc2, 0, 0, 0);
        acc3 = __builtin_amdgcn_mfma_f32_16x16x32_bf16(A, B3, acc3, 0, 0, 0);
    }

    float al = alpha[0];
    f32x4 accs[4] = {acc0, acc1, acc2, acc3};
    if (MODE == 2) {
#pragma unroll
        for (int ct = 0; ct < 4; ++ct) {
            int col = ct * 16 + m;
            float b = bias[col];
#pragma unroll
            for (int r = 0; r < 4; ++r) {
                int row = rowbase + quad * 4 + r;
                if (row < N) {
                    float v = accs[ct][r] + b;
                    v = v >= 0.f ? v : al * v;
                    H2[(size_t)row * 256 + col] = f2bf(v);
                }
            }
        }
    } else {
        float rv0 = 0.f, rv1 = 0.f, rv2 = 0.f, rv3 = 0.f;
#pragma unroll
        for (int ct = 0; ct < 4; ++ct) {
            int col = ct * 16 + m;
            float b = bias[col], wo = Wout[col];
            float v;
            v = accs[ct][0] + b; v = v >= 0.f ? v : al * v; rv0 = fmaf(v, wo, rv0);
            v = accs[ct][1] + b; v = v >= 0.f ? v : al * v; rv1 = fmaf(v, wo, rv1);
            v = accs[ct][2] + b; v = v >= 0.f ? v : al * v; rv2 = fmaf(v, wo, rv2);
            v = accs[ct][3] + b; v = v >= 0.f ? v : al * v; rv3 = fmaf(v, wo, rv3);
        }
        float rv[4] = {rv0, rv1, rv2, rv3};
#pragma unroll
        for (int r = 0; r < 4; ++r) {
            float v = rv[r];
            v += __shfl_xor(v, 8, 16);
            v += __shfl_xor(v, 4, 16);
            v += __shfl_xor(v, 2, 16);
            v += __shfl_xor(v, 1, 16);
            int row = rowbase + quad * 4 + r;
            if (m == 0 && row < N) atomicAdd(&bins[batch[row]], v);
        }
        __syncthreads();
        if (threadIdx.x < GRAPHS) {
            float bv = bins[threadIdx.x];
            if (bv != 0.0f) atomicAdd(&outp[threadIdx.x], bv);
        }
    }
}

extern "C" void kernel_launch(void* const* d_in, const int* in_sizes, int n_in,
                              void* d_out, int out_size, void* d_ws, size_t ws_size,
                              hipStream_t stream) {
    const float* x     = (const float*)d_in[0];
    const int*   ei    = (const int*)d_in[1];
    const int*   batch = (const int*)d_in[2];
    const float* W0    = (const float*)d_in[3];
    const float* b0    = (const float*)d_in[4];
    const float* W1    = (const float*)d_in[5];
    const float* b1    = (const float*)d_in[6];
    const float* a0    = (const float*)d_in[7];
    const float* a1    = (const float*)d_in[8];
    const float* Wout  = (const float*)d_in[9];
    const float* bout  = (const float*)d_in[10];

    const int N = in_sizes[0] / D;
    const int E = in_sizes[1] / 2;
    const int* src = ei;
    const int* dst = ei + E;

    size_t off = 0;
    auto alloc = [&](size_t bytes) -> void* {
        void* p = (char*)d_ws + off;
        off = (off + bytes + 255) & ~(size_t)255;
        return p;
    };
    const int NB = (N + 255) / 256;
    int*   deg      = (int*)alloc((size_t)(N + 1) * 4);   // deg[N] = scan ticket counter
    int*   pdeg     = (int*)alloc((size_t)N * 4);
    int*   rowstart = (int*)alloc((size_t)N * 4);
    float* dinv     = (float*)alloc((size_t)N * 4);
    int*   pos      = (int*)alloc((size_t)E * 4);
    unsigned int* epack = (unsigned int*)alloc(((size_t)E + 8ull * N) * 4);  // padded CSR, 4 B entries
    unsigned short* HA = (unsigned short*)alloc((size_t)N * 256 * 2);        // [N][4][64] bf16
    unsigned short* HB = (unsigned short*)alloc((size_t)N * 256 * 2);
    unsigned short* WF0 = (unsigned short*)alloc(16384 * 2);
    unsigned short* WF1 = (unsigned short*)alloc(16384 * 2);

    const int EB = (E + 255) / 256;
    const int NT = (N * D + 255) / 256;
    const int NG = (N + GROWS - 1) / GROWS;      // gather blocks (512 thr)
    const int NM = (N + 63) / 64;                // gemm blocks (256 thr)

    // --- CSR build + prep (3 kernels + memset) ---
    hipMemsetAsync(deg, 0, (size_t)(N + 1) * 4, stream);
    deg_prep_kernel<<<EB + 128 + NT, 256, 0, stream>>>(dst, deg, pos, E, EB,
                                                       W0, W1, WF0, WF1, x, HA, N * D);
    scan_all_kernel<<<NB, 256, 0, stream>>>(deg, dinv, pdeg, rowstart, epack, deg + N, N);
    scatter_kernel<<<EB, 256, 0, stream>>>(src, dst, pos, dinv, rowstart, epack, E);

    // --- layer 0: gathers fill HA slots 1..3, fused GEMM+bias+PReLU -> HB slot 0 (+ out init) ---
    gather_kernel<<<NG, 512, 0, stream>>>(HA + 0 * 64, HA + 1 * 64, rowstart, pdeg, dinv, epack, N);
    gather_kernel<<<NG, 512, 0, stream>>>(HA + 1 * 64, HA + 2 * 64, rowstart, pdeg, dinv, epack, N);
    gather_kernel<<<NG, 512, 0, stream>>>(HA + 2 * 64, HA + 3 * 64, rowstart, pdeg, dinv, epack, N);
    tag_gemm_kernel<2><<<NM, 256, 0, stream>>>(HA, WF0, b0, a0, nullptr, nullptr, bout,
                                               HB, (float*)d_out, N);

    // --- layer 1: gathers fill HB slots 1..3, fused GEMM+bias+PReLU+Wout-dot+pool -> out ---
    gather_kernel<<<NG, 512, 0, stream>>>(HB + 0 * 64, HB + 1 * 64, rowstart, pdeg, dinv, epack, N);
    gather_kernel<<<NG, 512, 0, stream>>>(HB + 1 * 64, HB + 2 * 64, rowstart, pdeg, dinv, epack, N);
    gather_kernel<<<NG, 512, 0, stream>>>(HB + 2 * 64, HB + 3 * 64, rowstart, pdeg, dinv, epack, N);
    tag_gemm_kernel<3><<<NM, 256, 0, stream>>>(HB, WF1, b1, a1, Wout, batch, bout,
                                               nullptr, (float*)d_out, N);
}